// Round 1
// baseline (733.298 us; speedup 1.0000x reference)
//
#include <hip/hip_runtime.h>
#include <math.h>

#define DIM 128
#define VOXSTRIDE (DIM*DIM*DIM)
#define CATT 23
#define NEARF 0.2f
#define FARF 6.0f

// d_init: linspace(NEAR, FAR, 256) as NEAR*(1-t)+FAR*t, t=i/255
__device__ __forceinline__ float d_init_val(int i) {
    float t = (float)i * (1.0f / 255.0f);
    return NEARF * (1.0f - t) + FARF * t;
}
// d_coarse: linspace(NEAR, FAR, 64), t=i/63
__device__ __forceinline__ float d_coarse_val(int i) {
    float t = (float)i * (1.0f / 63.0f);
    return NEARF * (1.0f - t) + FARF * t;
}

// trilinear, align_corners=True, border padding (clip coord, never zero)
__device__ __forceinline__ float tri_sdf(const float* __restrict__ vol,
                                         float x, float y, float z) {
    float c[3] = {x, y, z};
    float i0[3], fr[3];
#pragma unroll
    for (int a = 0; a < 3; a++) {
        float v = (c[a] + 1.0f) * 0.5f * 127.0f;   // (c+1)*0.5*(s-1)
        v = fminf(fmaxf(v, 0.0f), 127.0f);
        float f = floorf(v);
        i0[a] = f;
        fr[a] = v - f;
    }
    float res = 0.0f;
#pragma unroll
    for (int corner = 0; corner < 8; corner++) {
        float w = 1.0f;
        int gi[3];
#pragma unroll
        for (int a = 0; a < 3; a++) {
            int off = (corner >> a) & 1;
            float iv = i0[a] + (float)off;
            w *= off ? fr[a] : (1.0f - fr[a]);
            iv = fminf(fmaxf(iv, 0.0f), 127.0f);
            gi[a] = (int)iv;
        }
        int idx = (gi[0] * DIM + gi[1]) * DIM + gi[2];
        res += vol[idx] * w;
    }
    return res;
}

// trilinear, align_corners=False, zeros padding; accumulates 23 channels
__device__ __forceinline__ void tri_attr(const float* __restrict__ vol,
                                         float x, float y, float z,
                                         float* acc) {
    float c[3] = {x, y, z};
    float i0[3], fr[3];
#pragma unroll
    for (int a = 0; a < 3; a++) {
        float v = ((c[a] + 1.0f) * 128.0f - 1.0f) * 0.5f;  // ((c+1)*s-1)/2
        float f = floorf(v);
        i0[a] = f;
        fr[a] = v - f;
    }
#pragma unroll
    for (int corner = 0; corner < 8; corner++) {
        float w = 1.0f;
        bool valid = true;
        int gi[3];
#pragma unroll
        for (int a = 0; a < 3; a++) {
            int off = (corner >> a) & 1;
            float iv = i0[a] + (float)off;
            w *= off ? fr[a] : (1.0f - fr[a]);
            valid = valid && (iv >= 0.0f) && (iv <= 127.0f);
            iv = fminf(fmaxf(iv, 0.0f), 127.0f);
            gi[a] = (int)iv;
        }
        if (!valid) continue;  // reference zeroes w; contribution is 0
        int idx = (gi[0] * DIM + gi[1]) * DIM + gi[2];
#pragma unroll
        for (int ch = 0; ch < CATT; ch++) {
            acc[ch] += w * vol[ch * VOXSTRIDE + idx];
        }
    }
}

// Hillis-Steele inclusive scans over LDS, double-buffered. All 256 threads
// must call (uniform barriers); only tid<n participate. Returns final buffer.
__device__ __forceinline__ int incl_scan_prod(float (*buf)[256], int n, int tid) {
    int cur = 0;
    for (int off = 1; off < n; off <<= 1) {
        int nxt = cur ^ 1;
        if (tid < n) {
            float v = buf[cur][tid];
            if (tid >= off) v *= buf[cur][tid - off];
            buf[nxt][tid] = v;
        }
        __syncthreads();
        cur = nxt;
    }
    return cur;
}
__device__ __forceinline__ int incl_scan_add(float (*buf)[256], int n, int tid) {
    int cur = 0;
    for (int off = 1; off < n; off <<= 1) {
        int nxt = cur ^ 1;
        if (tid < n) {
            float v = buf[cur][tid];
            if (tid >= off) v += buf[cur][tid - off];
            buf[nxt][tid] = v;
        }
        __syncthreads();
        cur = nxt;
    }
    return cur;
}

__global__ __launch_bounds__(256) void volrender_kernel(
    const float* __restrict__ rays,
    const float* __restrict__ attr,
    const float* __restrict__ sdfv,
    const float* __restrict__ lnb,
    float* __restrict__ out, int R) {
    __shared__ float s_scan[2][256];
    __shared__ float s_cdf[256];
    __shared__ float s_dfine[64];
    __shared__ float s_dall[128];
    __shared__ float s_red[26][129];   // +1 pad: conflict-free row sums
    __shared__ float s_sum[26];

    const int r = blockIdx.x;
    const int tid = threadIdx.x;

    // --- ray preprocessing (all threads redundantly; broadcast loads) ---
    float ox = rays[r * 6 + 0], oy = rays[r * 6 + 1], oz = rays[r * 6 + 2];
    float dx = rays[r * 6 + 3], dy = rays[r * 6 + 4], dz = rays[r * 6 + 5];
    dx = (fabsf(dx) < 1e-6f) ? 1e-6f : dx;
    dy = (fabsf(dy) < 1e-6f) ? 1e-6f : dy;
    dz = (fabsf(dz) < 1e-6f) ? 1e-6f : dz;
    float dr = sqrtf(dx * dx + dy * dy + dz * dz);  // depth_ratio
    float invdr = 1.0f / dr;
    dx *= invdr; dy *= invdr; dz *= invdr;

    const float beta = expf(lnb[0] * 10.0f);
    const float alpha = 1.0f / beta;
    const float innorm = 2.0f / 5.12f;  // normalize: p*innorm - 1

    // ================= Phase 1: 256 init samples =================
    float d0 = d_init_val(tid);
    float sdf0;
    {
        float px = ox + dx * d0, py = oy + dy * d0, pz = oz + dz * d0;
        sdf0 = tri_sdf(sdfv, px * innorm - 1.0f, py * innorm - 1.0f,
                       pz * innorm - 1.0f);
    }
    float delta0 = (tid < 255) ? (d_init_val(tid + 1) - d0) : 1e10f;
    float e0 = expf(-fabsf(sdf0) / beta);
    float sig0 = alpha * ((sdf0 >= 0.0f) ? 0.5f * e0 : (1.0f - 0.5f * e0));
    float tr0 = expf(-sig0 * delta0);      // 1 - a
    float a0 = 1.0f - tr0;
    s_scan[0][tid] = tr0 + 1e-10f;         // f = 1 - a + 1e-10
    __syncthreads();
    int cur = incl_scan_prod(s_scan, 256, tid);
    float T0 = (tid == 0) ? 1.0f : s_scan[cur][tid - 1];  // exclusive prod
    float w0 = a0 * T0;
    __syncthreads();                        // done reading scan buffers
    s_scan[0][tid] = (tid < 255) ? (w0 + 1e-5f) : 0.0f;   // weights[:-1]
    __syncthreads();
    cur = incl_scan_add(s_scan, 256, tid);
    float wsum = s_scan[cur][254];
    float invw = 1.0f / wsum;
    if (tid == 0) s_cdf[0] = 0.0f;
    else s_cdf[tid] = s_scan[cur][tid - 1] * invw;  // cdf[255] = 1.0
    __syncthreads();

    // ---- sample_pdf: 64 deterministic inverse-CDF samples ----
    if (tid < 64) {
        float u = ((float)tid + 0.5f) * (1.0f / 64.0f);
        int lo = 0, hi = 256;                 // searchsorted(cdf, u, 'right')
        while (lo < hi) {
            int m = (lo + hi) >> 1;
            if (s_cdf[m] <= u) lo = m + 1; else hi = m;
        }
        int below = lo - 1; if (below > 255) below = 255; if (below < 0) below = 0;
        int above = lo;     if (above > 255) above = 255;
        float cg0 = s_cdf[below], cg1 = s_cdf[above];
        float bg0 = d_init_val(below), bg1 = d_init_val(above);
        float den = cg1 - cg0;
        if (den < 1e-5f) den = 1.0f;
        float t = (u - cg0) / den;
        s_dfine[tid] = bg0 + t * (bg1 - bg0);
    }
    __syncthreads();

    // ---- merge sorted coarse(64) + fine(64) -> d_all(128) ----
    if (tid < 64) {
        float v = d_coarse_val(tid);
        int lo = 0, hi = 64;                  // count fine < v
        while (lo < hi) {
            int m = (lo + hi) >> 1;
            if (s_dfine[m] < v) lo = m + 1; else hi = m;
        }
        s_dall[tid + lo] = v;
    } else if (tid < 128) {
        int j = tid - 64;
        float v = s_dfine[j];
        int lo = 0, hi = 64;                  // count coarse <= v
        while (lo < hi) {
            int m = (lo + hi) >> 1;
            if (d_coarse_val(m) <= v) lo = m + 1; else hi = m;
        }
        s_dall[j + lo] = v;
    }
    __syncthreads();

    // ================= Phase 2: 128 merged samples =================
    float a2 = 0.0f, dall = 0.0f;
    float xnx = 0.0f, xny = 0.0f, xnz = 0.0f;
    if (tid < 128) {
        dall = s_dall[tid];
        float px = ox + dx * dall, py = oy + dy * dall, pz = oz + dz * dall;
        xnx = px * innorm - 1.0f;
        xny = py * innorm - 1.0f;
        xnz = pz * innorm - 1.0f;
        float sdf2 = tri_sdf(sdfv, xnx, xny, xnz);
        s_red[25][tid] = sdf2;                      // for `valid`
        float delta2 = (tid < 127) ? (s_dall[tid + 1] - dall) : 1e10f;
        float e2 = expf(-fabsf(sdf2) / beta);
        float sig2 = alpha * ((sdf2 >= 0.0f) ? 0.5f * e2 : (1.0f - 0.5f * e2));
        float tr2 = expf(-sig2 * delta2);
        a2 = 1.0f - tr2;
        s_scan[0][tid] = tr2 + 1e-10f;
    }
    __syncthreads();
    cur = incl_scan_prod(s_scan, 128, tid);
    float tau = 0.0f;
    if (tid < 128) {
        float T2 = (tid == 0) ? 1.0f : s_scan[cur][tid - 1];
        tau = a2 * T2;
    }
    // attr gather (23ch) weighted by tau
    if (tid < 128) {
        float acc[CATT];
#pragma unroll
        for (int c = 0; c < CATT; c++) acc[c] = 0.0f;
        if (tau != 0.0f) tri_attr(attr, xnx, xny, xnz, acc);
#pragma unroll
        for (int c = 0; c < CATT; c++) s_red[c][tid] = tau * acc[c];
        s_red[23][tid] = tau;
        s_red[24][tid] = tau * dall;
    }
    __syncthreads();

    // ---- reductions: 26 rows x 128, one row per thread (pad -> no conflicts)
    if (tid < 26) {
        float s = 0.0f;
        for (int p = 0; p < 128; p++) s += s_red[tid][p];
        s_sum[tid] = s;
    }
    __syncthreads();

    // ---- outputs: [rgb 3R][depth R][valid R][sem 20R] ----
    if (tid < 3) {
        out[r * 3 + tid] = s_sum[tid];
    } else if (tid < 23) {
        out[5 * R + r * 20 + (tid - 3)] = s_sum[tid];
    } else if (tid == 23) {
        float dist = s_sum[24] / (s_sum[23] + 1e-10f);
        out[3 * R + r] = dist / dr;
    } else if (tid == 24) {
        out[4 * R + r] = (s_sum[25] != 128.0f) ? 1.0f : 0.0f;
    }
}

extern "C" void kernel_launch(void* const* d_in, const int* in_sizes, int n_in,
                              void* d_out, int out_size, void* d_ws, size_t ws_size,
                              hipStream_t stream) {
    const float* rays = (const float*)d_in[0];
    const float* attr = (const float*)d_in[1];
    const float* sdfv = (const float*)d_in[2];
    const float* lnb  = (const float*)d_in[3];
    float* out = (float*)d_out;
    int R = in_sizes[0] / 6;  // 4096 rays (B=1)
    volrender_kernel<<<dim3(R), dim3(256), 0, stream>>>(rays, attr, sdfv, lnb,
                                                        out, R);
}

// Round 2
// 424.683 us; speedup vs baseline: 1.7267x; 1.7267x over previous
//
#include <hip/hip_runtime.h>
#include <hip/hip_fp16.h>
#include <math.h>

#define DIM 128
#define VOXSTRIDE (DIM*DIM*DIM)
#define CATT 23
#define NEARF 0.2f
#define FARF 6.0f
#define REC_BYTES 64ull
#define WS_NEED (VOXSTRIDE * REC_BYTES)

// d_init: linspace(NEAR, FAR, 256)
__device__ __forceinline__ float d_init_val(int i) {
    float t = (float)i * (1.0f / 255.0f);
    return NEARF * (1.0f - t) + FARF * t;
}
// d_coarse: linspace(NEAR, FAR, 64)
__device__ __forceinline__ float d_coarse_val(int i) {
    float t = (float)i * (1.0f / 63.0f);
    return NEARF * (1.0f - t) + FARF * t;
}

// ---------- corner setup helpers ----------
// align_corners=True, border pad (sdf semantics)
__device__ __forceinline__ void setup_ac_border(float x, float y, float z,
                                                float* i0, float* fr) {
    float c[3] = {x, y, z};
#pragma unroll
    for (int a = 0; a < 3; a++) {
        float v = (c[a] + 1.0f) * 0.5f * 127.0f;
        v = fminf(fmaxf(v, 0.0f), 127.0f);
        float f = floorf(v);
        i0[a] = f;
        fr[a] = v - f;
    }
}
// align_corners=False, zeros pad (attr semantics)
__device__ __forceinline__ void setup_nac_zeros(float x, float y, float z,
                                                float* i0, float* fr) {
    float c[3] = {x, y, z};
#pragma unroll
    for (int a = 0; a < 3; a++) {
        float v = ((c[a] + 1.0f) * 128.0f - 1.0f) * 0.5f;
        float f = floorf(v);
        i0[a] = f;
        fr[a] = v - f;
    }
}

// trilinear SDF from fp32 volume (align_corners=True, border)
__device__ __forceinline__ float tri_sdf_vol(const float* __restrict__ vol,
                                             float x, float y, float z) {
    float i0[3], fr[3];
    setup_ac_border(x, y, z, i0, fr);
    float res = 0.0f;
#pragma unroll
    for (int corner = 0; corner < 8; corner++) {
        float w = 1.0f;
        int gi[3];
#pragma unroll
        for (int a = 0; a < 3; a++) {
            int off = (corner >> a) & 1;
            float iv = i0[a] + (float)off;
            w *= off ? fr[a] : (1.0f - fr[a]);
            iv = fminf(fmaxf(iv, 0.0f), 127.0f);
            gi[a] = (int)iv;
        }
        int idx = (gi[0] * DIM + gi[1]) * DIM + gi[2];
        res += vol[idx] * w;
    }
    return res;
}

// trilinear SDF from packed records (fp32 value at byte 48 of 64B record)
__device__ __forceinline__ float tri_sdf_rec(const float* __restrict__ recf,
                                             float x, float y, float z) {
    float i0[3], fr[3];
    setup_ac_border(x, y, z, i0, fr);
    float res = 0.0f;
#pragma unroll
    for (int corner = 0; corner < 8; corner++) {
        float w = 1.0f;
        int gi[3];
#pragma unroll
        for (int a = 0; a < 3; a++) {
            int off = (corner >> a) & 1;
            float iv = i0[a] + (float)off;
            w *= off ? fr[a] : (1.0f - fr[a]);
            iv = fminf(fmaxf(iv, 0.0f), 127.0f);
            gi[a] = (int)iv;
        }
        int idx = (gi[0] * DIM + gi[1]) * DIM + gi[2];
        res += recf[idx * 16 + 12] * w;
    }
    return res;
}

__device__ __forceinline__ void unpack16(uint4 a, uint4 b, float* v) {
    unsigned us[8] = {a.x, a.y, a.z, a.w, b.x, b.y, b.z, b.w};
#pragma unroll
    for (int i = 0; i < 8; i++) {
        v[2 * i]     = __half2float(__ushort_as_half((unsigned short)(us[i] & 0xffffu)));
        v[2 * i + 1] = __half2float(__ushort_as_half((unsigned short)(us[i] >> 16)));
    }
}

// attr trilinear for channels [c0,c1) from packed fp16 records
__device__ __forceinline__ void tri_attr_rec(const uint4* __restrict__ recs,
                                             float x, float y, float z,
                                             float* acc, int half) {
    float i0[3], fr[3];
    setup_nac_zeros(x, y, z, i0, fr);
#pragma unroll
    for (int corner = 0; corner < 8; corner++) {
        float w = 1.0f;
        bool valid = true;
        int gi[3];
#pragma unroll
        for (int a = 0; a < 3; a++) {
            int off = (corner >> a) & 1;
            float iv = i0[a] + (float)off;
            w *= off ? fr[a] : (1.0f - fr[a]);
            valid = valid && (iv >= 0.0f) && (iv <= 127.0f);
            iv = fminf(fmaxf(iv, 0.0f), 127.0f);
            gi[a] = (int)iv;
        }
        if (!valid) continue;
        int idx = (gi[0] * DIM + gi[1]) * DIM + gi[2];
        const uint4* q = recs + (size_t)idx * 4 + half;  // half0: q0,q1 (h0..15); half1: q1,q2 (h8..23)
        uint4 qa = q[0], qb = q[1];
        float vals[16];
        unpack16(qa, qb, vals);
        if (half == 0) {
#pragma unroll
            for (int c = 0; c < 12; c++) acc[c] += w * vals[c];
        } else {
#pragma unroll
            for (int c = 0; c < 11; c++) acc[c] += w * vals[c + 4];  // h[12..22]
        }
    }
}

// fallback: attr trilinear for channels [c0,c1) from fp32 planes
__device__ __forceinline__ void tri_attr_planes(const float* __restrict__ vol,
                                                float x, float y, float z,
                                                float* acc, int half) {
    float i0[3], fr[3];
    setup_nac_zeros(x, y, z, i0, fr);
    int c0 = half ? 12 : 0;
    int nc = half ? 11 : 12;
#pragma unroll
    for (int corner = 0; corner < 8; corner++) {
        float w = 1.0f;
        bool valid = true;
        int gi[3];
#pragma unroll
        for (int a = 0; a < 3; a++) {
            int off = (corner >> a) & 1;
            float iv = i0[a] + (float)off;
            w *= off ? fr[a] : (1.0f - fr[a]);
            valid = valid && (iv >= 0.0f) && (iv <= 127.0f);
            iv = fminf(fmaxf(iv, 0.0f), 127.0f);
            gi[a] = (int)iv;
        }
        if (!valid) continue;
        int idx = (gi[0] * DIM + gi[1]) * DIM + gi[2];
        for (int c = 0; c < nc; c++)
            acc[c] += w * vol[(c0 + c) * VOXSTRIDE + idx];
    }
}

// ---------- repack: [23][V] fp32 attrs + [V] fp32 sdf -> [V] 64B records ----
__global__ __launch_bounds__(256) void repack_kernel(
    const float* __restrict__ attr, const float* __restrict__ sdfv,
    uint4* __restrict__ recs) {
    int v = blockIdx.x * 256 + threadIdx.x;
    unsigned u[12];
#pragma unroll
    for (int p = 0; p < 12; p++) {
        float a = (2 * p < CATT) ? attr[(2 * p) * VOXSTRIDE + v] : 0.0f;
        float b = (2 * p + 1 < CATT) ? attr[(2 * p + 1) * VOXSTRIDE + v] : 0.0f;
        unsigned lo = (unsigned)__half_as_ushort(__float2half(a));
        unsigned hi = (unsigned)__half_as_ushort(__float2half(b));
        u[p] = lo | (hi << 16);
    }
    float s = sdfv[v];
    uint4* dst = recs + (size_t)v * 4;
    dst[0] = make_uint4(u[0], u[1], u[2], u[3]);
    dst[1] = make_uint4(u[4], u[5], u[6], u[7]);
    dst[2] = make_uint4(u[8], u[9], u[10], u[11]);
    dst[3] = make_uint4(__float_as_uint(s), 0u, 0u, 0u);
}

// ---------- scans ----------
__device__ __forceinline__ int incl_scan_prod(float (*buf)[256], int n, int tid) {
    int cur = 0;
    for (int off = 1; off < n; off <<= 1) {
        int nxt = cur ^ 1;
        if (tid < n) {
            float v = buf[cur][tid];
            if (tid >= off) v *= buf[cur][tid - off];
            buf[nxt][tid] = v;
        }
        __syncthreads();
        cur = nxt;
    }
    return cur;
}
__device__ __forceinline__ int incl_scan_add(float (*buf)[256], int n, int tid) {
    int cur = 0;
    for (int off = 1; off < n; off <<= 1) {
        int nxt = cur ^ 1;
        if (tid < n) {
            float v = buf[cur][tid];
            if (tid >= off) v += buf[cur][tid - off];
            buf[nxt][tid] = v;
        }
        __syncthreads();
        cur = nxt;
    }
    return cur;
}

template <bool PACKED>
__global__ __launch_bounds__(256) void volrender_kernel(
    const float* __restrict__ rays,
    const float* __restrict__ attr,
    const float* __restrict__ sdfv,
    const uint4* __restrict__ recs,
    const float* __restrict__ lnb,
    float* __restrict__ out, int R) {
    __shared__ float s_scan[2][256];
    __shared__ float s_cdf[256];
    __shared__ float s_dfine[64];
    __shared__ float s_dall[128];
    __shared__ float s_red[26][129];
    __shared__ float s_sum[26];
    __shared__ float s_xn[3][128];
    __shared__ float s_tau[128];

    const int r = blockIdx.x;
    const int tid = threadIdx.x;

    float ox = rays[r * 6 + 0], oy = rays[r * 6 + 1], oz = rays[r * 6 + 2];
    float dx = rays[r * 6 + 3], dy = rays[r * 6 + 4], dz = rays[r * 6 + 5];
    dx = (fabsf(dx) < 1e-6f) ? 1e-6f : dx;
    dy = (fabsf(dy) < 1e-6f) ? 1e-6f : dy;
    dz = (fabsf(dz) < 1e-6f) ? 1e-6f : dz;
    float dr = sqrtf(dx * dx + dy * dy + dz * dz);
    float invdr = 1.0f / dr;
    dx *= invdr; dy *= invdr; dz *= invdr;

    const float beta = expf(lnb[0] * 10.0f);
    const float alpha = 1.0f / beta;
    const float innorm = 2.0f / 5.12f;

    // ================= Phase 1: 256 init samples (fp32 sdf volume) ========
    float d0 = d_init_val(tid);
    float sdf0;
    {
        float px = ox + dx * d0, py = oy + dy * d0, pz = oz + dz * d0;
        sdf0 = tri_sdf_vol(sdfv, px * innorm - 1.0f, py * innorm - 1.0f,
                           pz * innorm - 1.0f);
    }
    float delta0 = (tid < 255) ? (d_init_val(tid + 1) - d0) : 1e10f;
    float e0 = expf(-fabsf(sdf0) / beta);
    float sig0 = alpha * ((sdf0 >= 0.0f) ? 0.5f * e0 : (1.0f - 0.5f * e0));
    float tr0 = expf(-sig0 * delta0);
    float a0 = 1.0f - tr0;
    s_scan[0][tid] = tr0 + 1e-10f;
    __syncthreads();
    int cur = incl_scan_prod(s_scan, 256, tid);
    float T0 = (tid == 0) ? 1.0f : s_scan[cur][tid - 1];
    float w0 = a0 * T0;
    __syncthreads();
    s_scan[0][tid] = (tid < 255) ? (w0 + 1e-5f) : 0.0f;
    __syncthreads();
    cur = incl_scan_add(s_scan, 256, tid);
    float wsum = s_scan[cur][254];
    float invw = 1.0f / wsum;
    if (tid == 0) s_cdf[0] = 0.0f;
    else s_cdf[tid] = s_scan[cur][tid - 1] * invw;
    __syncthreads();

    // ---- sample_pdf ----
    if (tid < 64) {
        float u = ((float)tid + 0.5f) * (1.0f / 64.0f);
        int lo = 0, hi = 256;
        while (lo < hi) {
            int m = (lo + hi) >> 1;
            if (s_cdf[m] <= u) lo = m + 1; else hi = m;
        }
        int below = lo - 1; if (below > 255) below = 255; if (below < 0) below = 0;
        int above = lo;     if (above > 255) above = 255;
        float cg0 = s_cdf[below], cg1 = s_cdf[above];
        float bg0 = d_init_val(below), bg1 = d_init_val(above);
        float den = cg1 - cg0;
        if (den < 1e-5f) den = 1.0f;
        float t = (u - cg0) / den;
        s_dfine[tid] = bg0 + t * (bg1 - bg0);
    }
    __syncthreads();

    // ---- merge coarse(64)+fine(64) ----
    if (tid < 64) {
        float v = d_coarse_val(tid);
        int lo = 0, hi = 64;
        while (lo < hi) {
            int m = (lo + hi) >> 1;
            if (s_dfine[m] < v) lo = m + 1; else hi = m;
        }
        s_dall[tid + lo] = v;
    } else if (tid < 128) {
        int j = tid - 64;
        float v = s_dfine[j];
        int lo = 0, hi = 64;
        while (lo < hi) {
            int m = (lo + hi) >> 1;
            if (d_coarse_val(m) <= v) lo = m + 1; else hi = m;
        }
        s_dall[j + lo] = v;
    }
    __syncthreads();

    // ================= Phase 2 ================
    float dall = 0.0f;
    if (tid < 128) {
        dall = s_dall[tid];
        float px = ox + dx * dall, py = oy + dy * dall, pz = oz + dz * dall;
        float xnx = px * innorm - 1.0f;
        float xny = py * innorm - 1.0f;
        float xnz = pz * innorm - 1.0f;
        s_xn[0][tid] = xnx; s_xn[1][tid] = xny; s_xn[2][tid] = xnz;
        float sdf2 = PACKED ? tri_sdf_rec((const float*)recs, xnx, xny, xnz)
                            : tri_sdf_vol(sdfv, xnx, xny, xnz);
        s_red[25][tid] = sdf2;
        float delta2 = (tid < 127) ? (s_dall[tid + 1] - dall) : 1e10f;
        float e2 = expf(-fabsf(sdf2) / beta);
        float sig2 = alpha * ((sdf2 >= 0.0f) ? 0.5f * e2 : (1.0f - 0.5f * e2));
        float tr2 = expf(-sig2 * delta2);
        s_scan[0][tid] = tr2 + 1e-10f;
        s_red[23][tid] = 1.0f - tr2;   // stash a2
    }
    __syncthreads();
    cur = incl_scan_prod(s_scan, 128, tid);
    if (tid < 128) {
        float T2 = (tid == 0) ? 1.0f : s_scan[cur][tid - 1];
        float tau = s_red[23][tid] * T2;
        s_tau[tid] = tau;
    }
    __syncthreads();

    // all 256 threads: channel-split attr gather
    {
        int samp = tid & 127;
        int half = tid >> 7;
        float tau = s_tau[samp];
        float xnx = s_xn[0][samp], xny = s_xn[1][samp], xnz = s_xn[2][samp];
        float acc[12];
#pragma unroll
        for (int c = 0; c < 12; c++) acc[c] = 0.0f;
        if (tau != 0.0f) {
            if (PACKED) tri_attr_rec(recs, xnx, xny, xnz, acc, half);
            else        tri_attr_planes(attr, xnx, xny, xnz, acc, half);
        }
        int c0 = half ? 12 : 0;
        int nc = half ? 11 : 12;
        for (int c = 0; c < nc; c++) s_red[c0 + c][samp] = tau * acc[c];
        if (half == 0) {
            s_red[23][samp] = tau;
            s_red[24][samp] = tau * dall;
        }
    }
    __syncthreads();

    if (tid < 26) {
        float s = 0.0f;
        for (int p = 0; p < 128; p++) s += s_red[tid][p];
        s_sum[tid] = s;
    }
    __syncthreads();

    if (tid < 3) {
        out[r * 3 + tid] = s_sum[tid];
    } else if (tid < 23) {
        out[5 * R + r * 20 + (tid - 3)] = s_sum[tid];
    } else if (tid == 23) {
        float dist = s_sum[24] / (s_sum[23] + 1e-10f);
        out[3 * R + r] = dist / dr;
    } else if (tid == 24) {
        out[4 * R + r] = (s_sum[25] != 128.0f) ? 1.0f : 0.0f;
    }
}

extern "C" void kernel_launch(void* const* d_in, const int* in_sizes, int n_in,
                              void* d_out, int out_size, void* d_ws, size_t ws_size,
                              hipStream_t stream) {
    const float* rays = (const float*)d_in[0];
    const float* attr = (const float*)d_in[1];
    const float* sdfv = (const float*)d_in[2];
    const float* lnb  = (const float*)d_in[3];
    float* out = (float*)d_out;
    int R = in_sizes[0] / 6;

    bool packed = (ws_size >= WS_NEED) && (((uintptr_t)d_ws & 15) == 0);
    if (packed) {
        uint4* recs = (uint4*)d_ws;
        repack_kernel<<<dim3(VOXSTRIDE / 256), dim3(256), 0, stream>>>(attr, sdfv, recs);
        volrender_kernel<true><<<dim3(R), dim3(256), 0, stream>>>(
            rays, attr, sdfv, recs, lnb, out, R);
    } else {
        volrender_kernel<false><<<dim3(R), dim3(256), 0, stream>>>(
            rays, attr, sdfv, (const uint4*)nullptr, lnb, out, R);
    }
}